// Round 2
// baseline (503.150 us; speedup 1.0000x reference)
//
#include <hip/hip_runtime.h>
#include <hip/hip_bf16.h>

#define EMBED 768
#define NHEADS 12
#define HDIM 64
#define WIN 64
#define BATCH 2
#define SEQ 2048
#define MROWS (BATCH*SEQ)      // 4096
#define NBH (BATCH*NHEADS)     // 24

typedef __attribute__((ext_vector_type(8))) short short8;
typedef __attribute__((ext_vector_type(4))) float f32x4;

__device__ __forceinline__ float bf2f(unsigned short u) {
    union { unsigned int i; float f; } z;
    z.i = ((unsigned int)u) << 16;
    return z.f;
}
__device__ __forceinline__ unsigned short f2bf(float f) {
    __hip_bfloat16 h = __float2bfloat16(f);
    return *reinterpret_cast<unsigned short*>(&h);
}

// ---------------- fp32 -> bf16 conversion ----------------
__global__ void cvt_f32_bf16(const float* __restrict__ src,
                             unsigned short* __restrict__ dst, int n4) {
    int i = blockIdx.x * blockDim.x + threadIdx.x;
    if (i < n4) {
        float4 v = reinterpret_cast<const float4*>(src)[i];
        ushort4 o;
        o.x = f2bf(v.x); o.y = f2bf(v.y); o.z = f2bf(v.z); o.w = f2bf(v.w);
        reinterpret_cast<ushort4*>(dst)[i] = o;
    }
}

// ---------------- bf16 NT GEMM: C[M,N] = A[M,K] * B[N,K]^T + bias ----------------
struct GArgs {
    const unsigned short* A[3];
    const unsigned short* Bm[3];
    const float* bias[3];
    void* C[3];
};

template<int F32OUT>
__global__ __launch_bounds__(256) void gemm_nt(GArgs ga, int M, int N, int K) {
    const int z = blockIdx.z;
    const unsigned short* __restrict__ A  = ga.A[z];
    const unsigned short* __restrict__ Bm = ga.Bm[z];
    const float* __restrict__ bias = ga.bias[z];

    const int bm = blockIdx.y * 128;
    const int bn = blockIdx.x * 128;

    __shared__ unsigned short As[128][40];  // pad 32->40 shorts (16B-aligned rows, conflict-reduced)
    __shared__ unsigned short Bs[128][40];

    const int tid = threadIdx.x;
    const int lane = tid & 63;
    const int wid = tid >> 6;
    const int wm = wid >> 1, wn = wid & 1;

    f32x4 acc[4][4] = {};

    const int fr = lane & 15;
    const int krow = (lane >> 4) * 8;

    for (int k0 = 0; k0 < K; k0 += 32) {
#pragma unroll
        for (int it = 0; it < 2; ++it) {
            int idx = tid + it * 256;     // chunk of 8 bf16
            int r = idx >> 2;
            int c = (idx & 3) * 8;
            int4 av = *reinterpret_cast<const int4*>(A + (size_t)(bm + r) * K + k0 + c);
            *reinterpret_cast<int4*>(&As[r][c]) = av;
            int4 bv = *reinterpret_cast<const int4*>(Bm + (size_t)(bn + r) * K + k0 + c);
            *reinterpret_cast<int4*>(&Bs[r][c]) = bv;
        }
        __syncthreads();

        short8 af[4], bfv[4];
#pragma unroll
        for (int mf = 0; mf < 4; ++mf)
            af[mf] = *reinterpret_cast<const short8*>(&As[wm * 64 + mf * 16 + fr][krow]);
#pragma unroll
        for (int nf = 0; nf < 4; ++nf)
            bfv[nf] = *reinterpret_cast<const short8*>(&Bs[wn * 64 + nf * 16 + fr][krow]);
#pragma unroll
        for (int mf = 0; mf < 4; ++mf)
#pragma unroll
            for (int nf = 0; nf < 4; ++nf)
                acc[mf][nf] = __builtin_amdgcn_mfma_f32_16x16x32_bf16(
                    af[mf], bfv[nf], acc[mf][nf], 0, 0, 0);
        __syncthreads();
    }

    // epilogue: D lane mapping col=lane&15, row=(lane>>4)*4+r
    const int fq = lane >> 4;
#pragma unroll
    for (int mf = 0; mf < 4; ++mf)
#pragma unroll
        for (int nf = 0; nf < 4; ++nf) {
            int col = bn + wn * 64 + nf * 16 + fr;
            float bv = bias[col];
#pragma unroll
            for (int r = 0; r < 4; ++r) {
                int row = bm + wm * 64 + mf * 16 + fq * 4 + r;
                float v = acc[mf][nf][r] + bv;
                if (F32OUT)
                    reinterpret_cast<float*>(ga.C[z])[(size_t)row * N + col] = v;
                else
                    reinterpret_cast<unsigned short*>(ga.C[z])[(size_t)row * N + col] = f2bf(v);
            }
        }
}

// ---------------- sum of V over keys, per (b,h,d) ----------------
__global__ void sumv_kernel(const unsigned short* __restrict__ Vb,
                            float* __restrict__ sumV) {
    __shared__ float r[4][HDIM];
    int bh = blockIdx.x;
    int b = bh / NHEADS, h = bh % NHEADS;
    int d = threadIdx.x & 63;
    int kc = threadIdx.x >> 6;
    float acc = 0.f;
    for (int j = kc; j < SEQ; j += 4)
        acc += bf2f(Vb[((size_t)(b * SEQ + j)) * EMBED + h * HDIM + d]);
    r[kc][d] = acc;
    __syncthreads();
    if (threadIdx.x < HDIM)
        sumV[bh * HDIM + threadIdx.x] =
            r[0][threadIdx.x] + r[1][threadIdx.x] + r[2][threadIdx.x] + r[3][threadIdx.x];
}

// ---------------- attention: one block per (b,h,query row) ----------------
__global__ __launch_bounds__(256) void attn_kernel(
    const unsigned short* __restrict__ Q,
    const unsigned short* __restrict__ Kb,
    const unsigned short* __restrict__ Vb,
    const unsigned char* __restrict__ kpm,
    const float* __restrict__ sumV,
    float* __restrict__ attn_out,
    unsigned short* __restrict__ ctx) {
    const int bid = blockIdx.x;
    const int qi = bid & (SEQ - 1);
    const int bh = bid >> 11;
    const int h = bh % NHEADS;
    const int b = bh / NHEADS;

    const int qlo = max(qi - WIN, 0);
    const int qhi = min(qi + WIN, SEQ - 1);
    const int nk = qhi - qlo + 1;   // <= 129

    __shared__ float q_l[HDIM];
    __shared__ float p_l[2 * WIN + 8];
    __shared__ float red[8];
    __shared__ float ctxred[4][HDIM];

    const int tid = threadIdx.x;
    const int lane = tid & 63;
    const int wid = tid >> 6;

    if (tid < HDIM)
        q_l[tid] = bf2f(Q[((size_t)(b * SEQ + qi)) * EMBED + h * HDIM + tid]);
    __syncthreads();

    // ---- scores for band keys ----
    float s = -1e30f;
    if (tid < nk) {
        const int j = qlo + tid;
        const int4* kr = reinterpret_cast<const int4*>(
            Kb + ((size_t)(b * SEQ + j)) * EMBED + h * HDIM);
        float acc = 0.f;
#pragma unroll
        for (int c = 0; c < 8; ++c) {
            int4 pk = kr[c];
            const unsigned short* u = reinterpret_cast<const unsigned short*>(&pk);
#pragma unroll
            for (int e = 0; e < 8; ++e) acc += q_l[c * 8 + e] * bf2f(u[e]);
        }
        s = acc * 0.125f;
        if (kpm[b * SEQ + j]) s = -10000.f;
    }

    // ---- block max ----
    float m = s;
#pragma unroll
    for (int off = 32; off; off >>= 1) m = fmaxf(m, __shfl_xor(m, off));
    if (lane == 0) red[wid] = m;
    __syncthreads();
    m = fmaxf(fmaxf(red[0], red[1]), fmaxf(red[2], red[3]));

    // ---- exp & sum ----
    float p = (tid < nk) ? __expf(s - m) : 0.f;
    float dsum = p;
#pragma unroll
    for (int off = 32; off; off >>= 1) dsum += __shfl_xor(dsum, off);
    __syncthreads();
    if (lane == 0) red[wid] = dsum;
    __syncthreads();
    dsum = red[0] + red[1] + red[2] + red[3];
    p = p / dsum;
    if (tid < nk) p_l[tid] = p;
    __syncthreads();

    // ---- write full attn row (1e-6 filler + band values), nontemporal ----
    {
        float* orow = attn_out + (((size_t)bh * SEQ) + qi) * SEQ;
        const int c0 = tid * 8;
        float v[8];
#pragma unroll
        for (int e = 0; e < 8; ++e) {
            int c = c0 + e;
            float val = 1e-6f;
            if (c >= qlo && c <= qhi) val = p_l[c - qlo] + 1e-6f;
            v[e] = val;
        }
        f32x4 v0 = { v[0], v[1], v[2], v[3] };
        f32x4 v1 = { v[4], v[5], v[6], v[7] };
        __builtin_nontemporal_store(v0, reinterpret_cast<f32x4*>(orow + c0));
        __builtin_nontemporal_store(v1, reinterpret_cast<f32x4*>(orow + c0 + 4));
    }

    // ---- PV: ctx = sum_band p*V + 1e-6 * sumV ----
    {
        const int d = tid & 63;
        const int kc = tid >> 6;
        float acc = 0.f;
        for (int j = kc; j < nk; j += 4)
            acc += p_l[j] * bf2f(Vb[((size_t)(b * SEQ + qlo + j)) * EMBED + h * HDIM + d]);
        ctxred[kc][d] = acc;
        __syncthreads();
        if (tid < HDIM) {
            float c = ctxred[0][tid] + ctxred[1][tid] + ctxred[2][tid] + ctxred[3][tid]
                    + 1e-6f * sumV[bh * HDIM + tid];
            ctx[((size_t)(b * SEQ + qi)) * EMBED + tid + h * HDIM] = f2bf(c);
        }
    }
}

// ---------------- host ----------------
extern "C" void kernel_launch(void* const* d_in, const int* in_sizes, int n_in,
                              void* d_out, int out_size, void* d_ws, size_t ws_size,
                              hipStream_t stream) {
    const float* q_in = (const float*)d_in[0];
    const float* k_in = (const float*)d_in[1];
    const float* v_in = (const float*)d_in[2];
    const unsigned char* kpm = (const unsigned char*)d_in[3];
    const float* Wq = (const float*)d_in[4];
    const float* bq = (const float*)d_in[5];
    const float* Wk = (const float*)d_in[6];
    const float* bk = (const float*)d_in[7];
    const float* Wv = (const float*)d_in[8];
    const float* bv = (const float*)d_in[9];
    const float* Wo = (const float*)d_in[10];
    const float* bo = (const float*)d_in[11];

    char* ws = (char*)d_ws;
    size_t off = 0;
    auto alloc = [&](size_t bytes) {
        void* p = ws + off;
        off += (bytes + 255) & ~255ULL;
        return p;
    };
    const size_t XB = (size_t)MROWS * EMBED * 2;  // bf16 [4096,768]
    const size_t WB = (size_t)EMBED * EMBED * 2;  // bf16 [768,768]
    unsigned short* xq = (unsigned short*)alloc(XB);
    unsigned short* xk = (unsigned short*)alloc(XB);
    unsigned short* xv = (unsigned short*)alloc(XB);
    unsigned short* wqb = (unsigned short*)alloc(WB);
    unsigned short* wkb = (unsigned short*)alloc(WB);
    unsigned short* wvb = (unsigned short*)alloc(WB);
    unsigned short* wob = (unsigned short*)alloc(WB);
    unsigned short* Qb = (unsigned short*)alloc(XB);
    unsigned short* Kb = (unsigned short*)alloc(XB);
    unsigned short* Vb = (unsigned short*)alloc(XB);
    unsigned short* ctx = (unsigned short*)alloc(XB);
    float* sumV = (float*)alloc((size_t)NBH * HDIM * 4);

    float* out0 = (float*)d_out;
    float* attn_out = out0 + (size_t)MROWS * EMBED;  // [B,H,S,S]

    // convert inputs + weights to bf16
    {
        int n4x = MROWS * EMBED / 4;
        int n4w = EMBED * EMBED / 4;
        dim3 blk(256);
        cvt_f32_bf16<<<dim3((n4x + 255) / 256), blk, 0, stream>>>(q_in, xq, n4x);
        cvt_f32_bf16<<<dim3((n4x + 255) / 256), blk, 0, stream>>>(k_in, xk, n4x);
        cvt_f32_bf16<<<dim3((n4x + 255) / 256), blk, 0, stream>>>(v_in, xv, n4x);
        cvt_f32_bf16<<<dim3((n4w + 255) / 256), blk, 0, stream>>>(Wq, wqb, n4w);
        cvt_f32_bf16<<<dim3((n4w + 255) / 256), blk, 0, stream>>>(Wk, wkb, n4w);
        cvt_f32_bf16<<<dim3((n4w + 255) / 256), blk, 0, stream>>>(Wv, wvb, n4w);
        cvt_f32_bf16<<<dim3((n4w + 255) / 256), blk, 0, stream>>>(Wo, wob, n4w);
    }

    // QKV projections (batched, z selects q/k/v)
    {
        GArgs ga;
        ga.A[0] = xq;  ga.A[1] = xk;  ga.A[2] = xv;
        ga.Bm[0] = wqb; ga.Bm[1] = wkb; ga.Bm[2] = wvb;
        ga.bias[0] = bq; ga.bias[1] = bk; ga.bias[2] = bv;
        ga.C[0] = Qb; ga.C[1] = Kb; ga.C[2] = Vb;
        gemm_nt<0><<<dim3(EMBED / 128, MROWS / 128, 3), dim3(256), 0, stream>>>(
            ga, MROWS, EMBED, EMBED);
    }

    sumv_kernel<<<dim3(NBH), dim3(256), 0, stream>>>(Vb, sumV);

    attn_kernel<<<dim3(BATCH * NHEADS * SEQ), dim3(256), 0, stream>>>(
        Qb, Kb, Vb, kpm, sumV, attn_out, ctx);

    // output projection -> fp32 out
    {
        GArgs ga;
        ga.A[0] = ctx;  ga.A[1] = ctx;  ga.A[2] = ctx;
        ga.Bm[0] = wob; ga.Bm[1] = wob; ga.Bm[2] = wob;
        ga.bias[0] = bo; ga.bias[1] = bo; ga.bias[2] = bo;
        ga.C[0] = out0; ga.C[1] = out0; ga.C[2] = out0;
        gemm_nt<1><<<dim3(EMBED / 128, MROWS / 128, 1), dim3(256), 0, stream>>>(
            ga, MROWS, EMBED, EMBED);
    }
}